// Round 2
// baseline (1126.168 us; speedup 1.0000x reference)
//
#include <hip/hip_runtime.h>

#define D_FEAT    62
#define N_CLASSES 500
#define N_DAGS    16384
#define N_NODES   48
#define MAX_PREDS 4

__device__ __forceinline__ float bf2f(unsigned short u) {
    union { unsigned int i; float f; } v;
    v.i = ((unsigned int)u) << 16;
    return v.f;
}

__device__ __forceinline__ unsigned short f2bf(float f) {
    union { float f; unsigned int i; } v;
    v.f = f;
    unsigned int x = v.i;
    return (unsigned short)((x + 0x7FFFu + ((x >> 16) & 1u)) >> 16);
}

__device__ __forceinline__ float bcast(float x, int k) {
    return __int_as_float(__builtin_amdgcn_readlane(__float_as_int(x), k));
}

// mode-dispatched scalar load: mode==0 -> bf16, mode==1 -> fp32.
// Explicit if/else so neither load can be speculated (OOB-safe).
__device__ __forceinline__ float ldm(const void* p, int i, int mode) {
    if (mode) {
        return ((const float*)p)[i];
    } else {
        return bf2f(((const unsigned short*)p)[i]);
    }
}

// ---------------------------------------------------------------------------
// K0: dtype sniff. Genuine bf16 N(0,1) atoms: even-index u16 halves decode to
// finite |v| < 64 always. fp32 atoms read as bf16 pairs: even halves are
// mantissa bits -> ~48% decode to |v|>=64 or NaN. Writes mode flag to ws.
// ---------------------------------------------------------------------------
__global__ void k_sniff(const void* __restrict__ atoms, int* __restrict__ flag) {
    __shared__ int red[256];
    const unsigned short* a = (const unsigned short*)atoms;
    int bad = 0;
    for (int i = threadIdx.x; i < 16384; i += 256) {
        const float v = bf2f(a[2 * i]);
        if (!(fabsf(v) < 64.f)) bad++;   // false for NaN too -> counted as bad
    }
    red[threadIdx.x] = bad;
    __syncthreads();
    for (int s = 128; s > 0; s >>= 1) {
        if (threadIdx.x < s) red[threadIdx.x] += red[threadIdx.x + s];
        __syncthreads();
    }
    if (threadIdx.x == 0) *flag = (red[0] > 16) ? 1 : 0;
}

// ---------------------------------------------------------------------------
// K1: per-DAG topological scan. One wave per DAG, 4 waves per block.
// lane = feature index. outs[48][62] per wave in LDS; W_merge staged in LDS
// as bf16 (converted from fp32 if mode==1). Broadcasts via readlane (pure
// register dataflow). fp32 accumulation throughout.
// ---------------------------------------------------------------------------
__global__ __launch_bounds__(256) void k_dag(
    const void* __restrict__ atoms,
    const int*  __restrict__ preds,
    const void* __restrict__ W_single,
    const void* __restrict__ b_single,
    const void* __restrict__ W_merge,
    const void* __restrict__ b_merge,
    const void* __restrict__ att_w,
    const void* __restrict__ dag_w,
    const int*  __restrict__ flag,
    float* __restrict__ last_out,     // [D,62] fp32
    float* __restrict__ score_out)    // [D] fp32
{
    __shared__ unsigned short swm[D_FEAT * 2 * D_FEAT];  // 7688 u16 = 15376 B
    __shared__ float souts[4][N_NODES * D_FEAT];         // 47616 B

    const int mode = *flag;   // grid-uniform

    // Stage W_merge into LDS as bf16 (coalesced)
    if (mode) {
        const float* w = (const float*)W_merge;
        for (int j = threadIdx.x; j < D_FEAT * 2 * D_FEAT; j += 256) swm[j] = f2bf(w[j]);
    } else {
        const unsigned short* w = (const unsigned short*)W_merge;
        for (int j = threadIdx.x; j < D_FEAT * 2 * D_FEAT; j += 256) swm[j] = w[j];
    }
    __syncthreads();   // the only barrier; everything below is per-wave

    const int lane = threadIdx.x & 63;
    const int wv   = threadIdx.x >> 6;
    const int lc   = (lane < D_FEAT) ? lane : 0;
    const int d    = blockIdx.x * 4 + wv;
    if (d >= N_DAGS) return;

    const float bm   = (lane < D_FEAT) ? ldm(b_merge,  lane, mode) : 0.f;
    const float aw   = (lane < D_FEAT) ? ldm(att_w,    lane, mode) : 0.f;
    const float dw   = (lane < D_FEAT) ? ldm(dag_w,    lane, mode) : 0.f;
    const float bsng = (lane < D_FEAT) ? ldm(b_single, lane, mode) : 0.f;

    float* outs = souts[wv];
    const int* pbase = preds + (size_t)d * (N_NODES * MAX_PREDS);
    const size_t abase = (size_t)d * (N_NODES * D_FEAT);
    const unsigned short* wrow = swm + lc * (2 * D_FEAT);

    float out_t = 0.f;

    #pragma unroll 1
    for (int t = 0; t < N_NODES; ++t) {
        const float at = (lane < D_FEAT) ? ldm(atoms, abase + t * D_FEAT + lane, mode) : 0.f;
        const int px = pbase[t * 4 + 0];
        const int py = pbase[t * 4 + 1];
        const int pz = pbase[t * 4 + 2];
        const int pw = pbase[t * 4 + 3];
        const int pm = max(max(px, py), max(pz, pw));

        if (pm >= 0) {  // wave-uniform: node has >= 1 predecessor
            const float g0 = outs[max(px, 0) * D_FEAT + lc];
            const float g1 = outs[max(py, 0) * D_FEAT + lc];
            const float g2 = outs[max(pz, 0) * D_FEAT + lc];
            const float g3 = outs[max(pw, 0) * D_FEAT + lc];

            // attention scores: dot(g_j, att_w) via butterfly (lanes 62/63 add 0)
            float s0 = g0 * aw, s1 = g1 * aw, s2 = g2 * aw, s3 = g3 * aw;
            #pragma unroll
            for (int off = 32; off > 0; off >>= 1) {
                s0 += __shfl_xor(s0, off);
                s1 += __shfl_xor(s1, off);
                s2 += __shfl_xor(s2, off);
                s3 += __shfl_xor(s3, off);
            }
            s0 = (px >= 0) ? s0 : -1e30f;
            s1 = (py >= 0) ? s1 : -1e30f;
            s2 = (pz >= 0) ? s2 : -1e30f;
            s3 = (pw >= 0) ? s3 : -1e30f;
            const float mx = fmaxf(fmaxf(s0, s1), fmaxf(s2, s3));
            const float e0 = (px >= 0) ? __expf(s0 - mx) : 0.f;
            const float e1 = (py >= 0) ? __expf(s1 - mx) : 0.f;
            const float e2 = (pz >= 0) ? __expf(s2 - mx) : 0.f;
            const float e3 = (pw >= 0) ? __expf(s3 - mx) : 0.f;
            const float inv = 1.f / (e0 + e1 + e2 + e3);
            const float agg = fmaf(e0, g0, fmaf(e1, g1, fmaf(e2, g2, e3 * g3))) * inv;

            // merged = relu(W_merge @ [agg; atom] + b_merge)
            float a0 = bm, a1 = 0.f, a2 = 0.f, a3 = 0.f;
            #pragma unroll 2
            for (int k = 0; k < D_FEAT; k += 2) {
                a0 = fmaf(bf2f(wrow[k]),              bcast(agg, k),     a0);
                a1 = fmaf(bf2f(wrow[k + 1]),          bcast(agg, k + 1), a1);
                a2 = fmaf(bf2f(wrow[D_FEAT + k]),     bcast(at,  k),     a2);
                a3 = fmaf(bf2f(wrow[D_FEAT + k + 1]), bcast(at,  k + 1), a3);
            }
            out_t = fmaxf((a0 + a1) + (a2 + a3), 0.f);
        } else {  // source node: relu(W_single @ atom + b_single); rare path
            float acc = bsng;
            for (int f = 0; f < D_FEAT; ++f)
                acc = fmaf(ldm(W_single, lc * D_FEAT + f, mode), bcast(at, f), acc);
            out_t = fmaxf(acc, 0.f);
        }
        if (lane < D_FEAT) outs[t * D_FEAT + lane] = out_t;
    }

    // sink node (t = 47) output = DAG representation
    if (lane < D_FEAT) last_out[(size_t)d * D_FEAT + lane] = out_t;
    float sp = out_t * dw;
    #pragma unroll
    for (int off = 32; off > 0; off >>= 1) sp += __shfl_xor(sp, off);
    if (lane == 0) score_out[d] = sp;
}

// ---------------------------------------------------------------------------
// K2: softmax stats over the 16384 DAG scores (max + sum of exp), zero pooled
// ---------------------------------------------------------------------------
__global__ void k_prep(const float* __restrict__ score,
                       float* __restrict__ stats,   // [0]=M, [1]=denom
                       float* __restrict__ pooled)  // [62]
{
    __shared__ float red[256];
    float m = -3.0e38f;
    for (int d = threadIdx.x; d < N_DAGS; d += 256) m = fmaxf(m, score[d]);
    red[threadIdx.x] = m;
    __syncthreads();
    for (int s = 128; s > 0; s >>= 1) {
        if (threadIdx.x < s) red[threadIdx.x] = fmaxf(red[threadIdx.x], red[threadIdx.x + s]);
        __syncthreads();
    }
    const float M = red[0];
    __syncthreads();
    float sum = 0.f;
    for (int d = threadIdx.x; d < N_DAGS; d += 256) sum += __expf(score[d] - M);
    red[threadIdx.x] = sum;
    __syncthreads();
    for (int s = 128; s > 0; s >>= 1) {
        if (threadIdx.x < s) red[threadIdx.x] += red[threadIdx.x + s];
        __syncthreads();
    }
    if (threadIdx.x == 0) { stats[0] = M; stats[1] = red[0]; }
    if (threadIdx.x < D_FEAT) pooled[threadIdx.x] = 0.f;
}

// ---------------------------------------------------------------------------
// K3: pooled[i] = sum_d exp(score_d - M) * last[d][i]   (un-normalized)
// ---------------------------------------------------------------------------
__global__ __launch_bounds__(256) void k_pool(
    const float* __restrict__ last,
    const float* __restrict__ score,
    const float* __restrict__ stats,
    float* __restrict__ pooled)
{
    const int lane  = threadIdx.x & 63;
    const int wv    = threadIdx.x >> 6;
    const int chunk = blockIdx.x * 4 + wv;     // 0..255, 64 DAGs each
    const float M = stats[0];
    const int d0 = chunk * 64;
    float acc = 0.f;
    for (int j = 0; j < 64; ++j) {
        const int d = d0 + j;
        const float e = __expf(score[d] - M);
        const float v = (lane < D_FEAT) ? last[(size_t)d * D_FEAT + lane] : 0.f;
        acc = fmaf(e, v, acc);
    }
    if (lane < D_FEAT) atomicAdd(pooled + lane, acc);
}

// ---------------------------------------------------------------------------
// K4: out[r] = sigmoid(W_final[r] . (pooled/denom) + b_final[r])
// ---------------------------------------------------------------------------
__global__ void k_final(const float* __restrict__ pooled,
                        const float* __restrict__ stats,
                        const void* __restrict__ W_final,
                        const void* __restrict__ b_final,
                        const int* __restrict__ flag,
                        void* __restrict__ out)
{
    const int r = blockIdx.x * 256 + threadIdx.x;
    if (r >= N_CLASSES) return;
    const int mode = *flag;
    const float inv = 1.f / stats[1];
    float acc = ldm(b_final, r, mode);
    for (int i = 0; i < D_FEAT; ++i)
        acc = fmaf(ldm(W_final, r * D_FEAT + i, mode), pooled[i] * inv, acc);
    const float s = 1.f / (1.f + __expf(-acc));
    if (mode) ((float*)out)[r] = s;
    else      ((unsigned short*)out)[r] = f2bf(s);
}

extern "C" void kernel_launch(void* const* d_in, const int* in_sizes, int n_in,
                              void* d_out, int out_size, void* d_ws, size_t ws_size,
                              hipStream_t stream) {
    const void* atoms    = d_in[0];
    const int*  preds    = (const int*)d_in[1];
    const void* W_single = d_in[2];
    const void* b_single = d_in[3];
    const void* W_merge  = d_in[4];
    const void* b_merge  = d_in[5];
    const void* att_w    = d_in[6];
    const void* dag_w    = d_in[7];
    const void* W_final  = d_in[8];
    const void* b_final  = d_in[9];

    float* last   = (float*)d_ws;                    // 16384*62 fp32
    float* score  = last + (size_t)N_DAGS * D_FEAT;  // 16384
    float* stats  = score + N_DAGS;                  // 2
    float* pooled = stats + 2;                       // 62
    int*   flag   = (int*)(pooled + 62);             // 1

    k_sniff<<<1,    256, 0, stream>>>(atoms, flag);
    k_dag  <<<4096, 256, 0, stream>>>(atoms, preds, W_single, b_single, W_merge,
                                      b_merge, att_w, dag_w, flag, last, score);
    k_prep <<<1,    256, 0, stream>>>(score, stats, pooled);
    k_pool <<<64,   256, 0, stream>>>(last, score, stats, pooled);
    k_final<<<2,    256, 0, stream>>>(pooled, stats, W_final, b_final, flag, d_out);
}

// Round 3
// 753.772 us; speedup vs baseline: 1.4940x; 1.4940x over previous
//
#include <hip/hip_runtime.h>

#define D_FEAT    62
#define N_CLASSES 500
#define N_DAGS    16384
#define N_NODES   48
#define MAX_PREDS 4

__device__ __forceinline__ float bf2f(unsigned short u) {
    union { unsigned int i; float f; } v;
    v.i = ((unsigned int)u) << 16;
    return v.f;
}

__device__ __forceinline__ unsigned short f2bf(float f) {
    union { float f; unsigned int i; } v;
    v.f = f;
    unsigned int x = v.i;
    return (unsigned short)((x + 0x7FFFu + ((x >> 16) & 1u)) >> 16);
}

__device__ __forceinline__ float bcast(float x, int k) {
    return __int_as_float(__builtin_amdgcn_readlane(__float_as_int(x), k));
}

__device__ __forceinline__ float pk_lo(unsigned int u) { return __uint_as_float(u << 16); }
__device__ __forceinline__ float pk_hi(unsigned int u) { return __uint_as_float(u & 0xFFFF0000u); }

// mode-dispatched scalar load: mode==0 -> bf16, mode==1 -> fp32.
__device__ __forceinline__ float ldm(const void* p, long i, int mode) {
    if (mode) return ((const float*)p)[i];
    else      return bf2f(((const unsigned short*)p)[i]);
}

// ---------------------------------------------------------------------------
// K1: per-DAG topological scan. One wave per DAG, 4 waves/block, no barriers.
// lane = feature. W_merge row register-cached as packed bf16 (62 u32).
// Per-node attention score precomputed at production time into LDS (1
// butterfly/node instead of 4). Atom+preds software-pipelined.
// ---------------------------------------------------------------------------
__global__ __launch_bounds__(256, 3) void k_dag(
    const void* __restrict__ atoms,
    const int*  __restrict__ preds,
    const void* __restrict__ W_single,
    const void* __restrict__ b_single,
    const void* __restrict__ W_merge,
    const void* __restrict__ b_merge,
    const void* __restrict__ att_w,
    const void* __restrict__ dag_w,
    float* __restrict__ last_out,     // [D,62] fp32
    float* __restrict__ score_out)    // [D] fp32
{
    __shared__ float souts[4][N_NODES * D_FEAT];  // 47616 B
    __shared__ float ssc[4][N_NODES];             // 768 B  -> 48384 B total

    const int lane = threadIdx.x & 63;
    const int wv   = threadIdx.x >> 6;
    const int lc   = (lane < D_FEAT) ? lane : (D_FEAT - 1);
    const int d    = blockIdx.x * 4 + wv;

    // Inline dtype sniff: same 256 bytes for every wave -> uniform decision.
    // bf16 atoms: even u16 halves are N(0,1) values, always |v|<64.
    // fp32 atoms read as u16: even halves are mantissa bits, ~48% |v|>=64/NaN.
    int mode;
    {
        const unsigned short* a16 = (const unsigned short*)atoms;
        const float v0 = bf2f(a16[2 * lane]);
        const float v1 = bf2f(a16[128 + 2 * lane]);
        const int bad = (!(fabsf(v0) < 64.f)) + (!(fabsf(v1) < 64.f));
        const int cnt = __popcll(__ballot(bad > 0)) + __popcll(__ballot(bad > 1));
        mode = (cnt > 16) ? 1 : 0;   // fp32: mu=61, sigma=5.7 -> 8 sigma margin
    }

    // Register-cache this lane's W_merge row as packed bf16.
    // Row = 124 entries: [0..61] multiply agg, [62..123] multiply atom.
    unsigned int wma[31], wmb[31];
    if (mode == 0) {
        const unsigned int* row = (const unsigned int*)W_merge + lc * 62;
        #pragma unroll
        for (int j = 0; j < 31; ++j) { wma[j] = row[j]; wmb[j] = row[31 + j]; }
    } else {
        const float* row = (const float*)W_merge + lc * 124;
        #pragma unroll
        for (int j = 0; j < 31; ++j) {
            wma[j] = (unsigned)f2bf(row[2*j])      | ((unsigned)f2bf(row[2*j+1])    << 16);
            wmb[j] = (unsigned)f2bf(row[62+2*j])   | ((unsigned)f2bf(row[63+2*j])   << 16);
        }
    }

    const float bm   = (lane < D_FEAT) ? ldm(b_merge,  lane, mode) : 0.f;
    const float aw   = (lane < D_FEAT) ? ldm(att_w,    lane, mode) : 0.f;
    const float dw   = (lane < D_FEAT) ? ldm(dag_w,    lane, mode) : 0.f;
    const float bsng = (lane < D_FEAT) ? ldm(b_single, lane, mode) : 0.f;

    float* outs = souts[wv];
    float* scs  = ssc[wv];
    const int* pbase = preds + (size_t)d * (N_NODES * MAX_PREDS);
    const size_t abase = (size_t)d * (N_NODES * D_FEAT);

    // software pipeline: preload node 0
    int4  pv  = *(const int4*)pbase;
    float atv = (lane < D_FEAT) ? ldm(atoms, abase + lane, mode) : 0.f;

    float out_t = 0.f;

    #pragma unroll 1
    for (int t = 0; t < N_NODES; ++t) {
        // prefetch node t+1
        int4 pn = pv; float atn = atv;
        if (t < N_NODES - 1) {
            pn  = *(const int4*)(pbase + (t + 1) * 4);
            atn = (lane < D_FEAT) ? ldm(atoms, abase + (size_t)(t + 1) * D_FEAT + lane, mode) : 0.f;
        }

        const int px = pv.x, py = pv.y, pz = pv.z, pw = pv.w;
        const int pm = max(max(px, py), max(pz, pw));

        if (pm >= 0) {  // wave-uniform: node has >= 1 predecessor
            const float g0 = outs[max(px, 0) * D_FEAT + lc];
            const float g1 = outs[max(py, 0) * D_FEAT + lc];
            const float g2 = outs[max(pz, 0) * D_FEAT + lc];
            const float g3 = outs[max(pw, 0) * D_FEAT + lc];

            // attention scores: precomputed at production, scalar broadcast reads
            const float q0 = (px >= 0) ? scs[max(px, 0)] : -1e30f;
            const float q1 = (py >= 0) ? scs[max(py, 0)] : -1e30f;
            const float q2 = (pz >= 0) ? scs[max(pz, 0)] : -1e30f;
            const float q3 = (pw >= 0) ? scs[max(pw, 0)] : -1e30f;
            const float mx = fmaxf(fmaxf(q0, q1), fmaxf(q2, q3));
            const float e0 = (px >= 0) ? __expf(q0 - mx) : 0.f;
            const float e1 = (py >= 0) ? __expf(q1 - mx) : 0.f;
            const float e2 = (pz >= 0) ? __expf(q2 - mx) : 0.f;
            const float e3 = (pw >= 0) ? __expf(q3 - mx) : 0.f;
            const float inv = 1.f / (e0 + e1 + e2 + e3);
            const float agg = fmaf(e0, g0, fmaf(e1, g1, fmaf(e2, g2, e3 * g3))) * inv;

            // merged = relu(W_merge @ [agg; atom] + b_merge), row in registers
            float a0 = bm, a1 = 0.f, a2 = 0.f, a3 = 0.f;
            #pragma unroll
            for (int j = 0; j < 31; ++j) {
                const unsigned int ua = wma[j], ub = wmb[j];
                a0 = fmaf(pk_lo(ua), bcast(agg, 2 * j),     a0);
                a1 = fmaf(pk_hi(ua), bcast(agg, 2 * j + 1), a1);
                a2 = fmaf(pk_lo(ub), bcast(atv, 2 * j),     a2);
                a3 = fmaf(pk_hi(ub), bcast(atv, 2 * j + 1), a3);
            }
            out_t = fmaxf((a0 + a1) + (a2 + a3), 0.f);
        } else {  // source node: relu(W_single @ atom + b_single); rare path
            float acc = bsng;
            for (int f = 0; f < D_FEAT; ++f)
                acc = fmaf(ldm(W_single, lc * D_FEAT + f, mode), bcast(atv, f), acc);
            out_t = fmaxf(acc, 0.f);
        }

        if (lane < D_FEAT) outs[t * D_FEAT + lane] = out_t;

        // per-node attention score for future gathers (1 butterfly)
        float sp = out_t * aw;
        #pragma unroll
        for (int off = 32; off > 0; off >>= 1) sp += __shfl_xor(sp, off);
        if (lane == 0) scs[t] = sp;

        pv = pn; atv = atn;
    }

    // sink node output = DAG representation
    if (lane < D_FEAT) last_out[(size_t)d * D_FEAT + lane] = out_t;
    float sp = out_t * dw;
    #pragma unroll
    for (int off = 32; off > 0; off >>= 1) sp += __shfl_xor(sp, off);
    if (lane == 0) score_out[d] = sp;
}

// ---------------------------------------------------------------------------
// K2: per-chunk online softmax partials. chunk = 64 DAGs per wave, 256 chunks.
// Writes (m_c, sum_e, sum_e*v[62]) per chunk. No atomics, no init needed.
// ---------------------------------------------------------------------------
__global__ __launch_bounds__(256) void k_pool(
    const float* __restrict__ last,
    const float* __restrict__ score,
    float* __restrict__ vpart,    // [256,62]
    float* __restrict__ mpart,    // [256]
    float* __restrict__ spart)    // [256]
{
    const int lane = threadIdx.x & 63;
    const int wv   = threadIdx.x >> 6;
    const int c    = blockIdx.x * 4 + wv;
    const int d0   = c * 64;

    const float s = score[d0 + lane];
    float m = s;
    #pragma unroll
    for (int off = 32; off > 0; off >>= 1) m = fmaxf(m, __shfl_xor(m, off));
    const float e = __expf(s - m);
    float den = e;
    #pragma unroll
    for (int off = 32; off > 0; off >>= 1) den += __shfl_xor(den, off);

    float acc = 0.f;
    #pragma unroll 4
    for (int j = 0; j < 64; ++j) {
        const float v = (lane < D_FEAT) ? last[(size_t)(d0 + j) * D_FEAT + lane] : 0.f;
        acc = fmaf(bcast(e, j), v, acc);
    }
    if (lane < D_FEAT) vpart[c * D_FEAT + lane] = acc;
    if (lane == 0) { mpart[c] = m; spart[c] = den; }
}

// ---------------------------------------------------------------------------
// K3: combine 256 chunks (online-softmax merge) + 500-class sigmoid head.
// ---------------------------------------------------------------------------
__global__ __launch_bounds__(256) void k_final(
    const void* __restrict__ atoms,
    const float* __restrict__ vpart,
    const float* __restrict__ mpart,
    const float* __restrict__ spart,
    const void* __restrict__ W_final,
    const void* __restrict__ b_final,
    void* __restrict__ out)
{
    __shared__ float red[256];
    __shared__ float wgt[256];
    __shared__ float pooled[D_FEAT];
    const int tid = threadIdx.x;

    // dtype sniff (block-uniform vote over the same 512 checks)
    const unsigned short* a16 = (const unsigned short*)atoms;
    const int bad = (!(fabsf(bf2f(a16[2 * (tid & 63)])) < 64.f))
                  + (!(fabsf(bf2f(a16[128 + 2 * (tid & 63)])) < 64.f));
    red[tid] = (float)bad;
    __syncthreads();
    for (int s = 128; s > 0; s >>= 1) {
        if (tid < s) red[tid] += red[tid + s];
        __syncthreads();
    }
    const int mode = (red[0] > 64.f) ? 1 : 0;
    __syncthreads();

    // global max over chunk maxima
    const float m = mpart[tid];
    red[tid] = m;
    __syncthreads();
    for (int s = 128; s > 0; s >>= 1) {
        if (tid < s) red[tid] = fmaxf(red[tid], red[tid + s]);
        __syncthreads();
    }
    const float M = red[0];
    __syncthreads();

    const float w = __expf(m - M);
    wgt[tid] = w;
    red[tid] = w * spart[tid];
    __syncthreads();
    for (int s = 128; s > 0; s >>= 1) {
        if (tid < s) red[tid] += red[tid + s];
        __syncthreads();
    }
    const float denom = red[0];
    __syncthreads();

    if (tid < D_FEAT) {
        float acc = 0.f;
        for (int c = 0; c < 256; ++c) acc = fmaf(wgt[c], vpart[c * D_FEAT + tid], acc);
        pooled[tid] = acc / denom;
    }
    __syncthreads();

    for (int r = tid; r < N_CLASSES; r += 256) {
        float acc = ldm(b_final, r, mode);
        #pragma unroll
        for (int i = 0; i < D_FEAT; ++i)
            acc = fmaf(ldm(W_final, r * D_FEAT + i, mode), pooled[i], acc);
        const float sg = 1.f / (1.f + __expf(-acc));
        if (mode) ((float*)out)[r] = sg;
        else      ((unsigned short*)out)[r] = f2bf(sg);
    }
}

extern "C" void kernel_launch(void* const* d_in, const int* in_sizes, int n_in,
                              void* d_out, int out_size, void* d_ws, size_t ws_size,
                              hipStream_t stream) {
    const void* atoms    = d_in[0];
    const int*  preds    = (const int*)d_in[1];
    const void* W_single = d_in[2];
    const void* b_single = d_in[3];
    const void* W_merge  = d_in[4];
    const void* b_merge  = d_in[5];
    const void* att_w    = d_in[6];
    const void* dag_w    = d_in[7];
    const void* W_final  = d_in[8];
    const void* b_final  = d_in[9];

    float* last  = (float*)d_ws;                     // 16384*62
    float* score = last + (size_t)N_DAGS * D_FEAT;   // 16384
    float* vpart = score + N_DAGS;                   // 256*62
    float* mpart = vpart + 256 * D_FEAT;             // 256
    float* spart = mpart + 256;                      // 256

    k_dag  <<<4096, 256, 0, stream>>>(atoms, preds, W_single, b_single, W_merge,
                                      b_merge, att_w, dag_w, last, score);
    k_pool <<<64,   256, 0, stream>>>(last, score, vpart, mpart, spart);
    k_final<<<1,    256, 0, stream>>>(atoms, vpart, mpart, spart, W_final, b_final, d_out);
}

// Round 4
// 694.344 us; speedup vs baseline: 1.6219x; 1.0856x over previous
//
#include <hip/hip_runtime.h>

#define D_FEAT    62
#define N_CLASSES 500
#define N_DAGS    16384
#define N_NODES   48
#define MAX_PREDS 4
#define DPB       8                  // dags per block (one wave of 64)
#define ROWB      6160               // outs row stride bytes: 48*64*2 + 16 pad (bank rotate)
#define SCS_OFF   (DPB * ROWB)       // 49280
#define SCS_STR   49                 // scs row stride (floats)

typedef __attribute__((ext_vector_type(8))) short short8;
typedef __attribute__((ext_vector_type(4))) float f32x4;

union FragU { unsigned int u[4]; short8 v; };

__device__ __forceinline__ float bf2f(unsigned short u) {
    union { unsigned int i; float f; } v;
    v.i = ((unsigned int)u) << 16;
    return v.f;
}

__device__ __forceinline__ unsigned short f2bf(float f) {
    union { float f; unsigned int i; } v;
    v.f = f;
    unsigned int x = v.i;
    return (unsigned short)((x + 0x7FFFu + ((x >> 16) & 1u)) >> 16);
}

// pack two f32 into one u32 of two RNE bf16 (lo = a, hi = b)
__device__ __forceinline__ unsigned int pack2bf(float a, float b) {
    unsigned int ia = __float_as_uint(a), ib = __float_as_uint(b);
    ia += 0x7FFFu + ((ia >> 16) & 1u);
    ib += 0x7FFFu + ((ib >> 16) & 1u);
    return (ia >> 16) | (ib & 0xFFFF0000u);
}

__device__ __forceinline__ float pk_lo(unsigned int u) { return __uint_as_float(u << 16); }
__device__ __forceinline__ float pk_hi(unsigned int u) { return __uint_as_float(u & 0xFFFF0000u); }

__device__ __forceinline__ float bcast(float x, int k) {
    return __int_as_float(__builtin_amdgcn_readlane(__float_as_int(x), k));
}

// mode-dispatched scalar load: mode==0 -> bf16, mode==1 -> fp32
__device__ __forceinline__ float ldm(const void* p, long i, int mode) {
    if (mode) return ((const float*)p)[i];
    else      return bf2f(((const unsigned short*)p)[i]);
}

// W_merge value in padded-X coords: X = [agg(62), 0,0, atom(62), 0,0]
__device__ __forceinline__ float wm_val(const void* W, int n, int k, int mode) {
    if (n >= D_FEAT) return 0.f;
    if (k < 62)  return ldm(W, n * 124 + k, mode);
    if (k < 64)  return 0.f;
    if (k < 126) return ldm(W, n * 124 + (k - 2), mode);
    return 0.f;
}

__device__ __forceinline__ float ws_val(const void* W, int n, int k, int mode) {
    if (n >= D_FEAT || k >= D_FEAT) return 0.f;
    return ldm(W, n * 62 + k, mode);
}

// Load atom chunks for (row = d*48+t): f2 = atom[c*8 .. c*8+7] (all < 32),
// f3 = atom[32+c*8 ..] with >=62 zero-padded. Scalar loads (mode-safe, OOB-safe).
__device__ __forceinline__ void load_atom(FragU& f2, FragU& f3, const void* atoms,
                                          long row, int c, int mode, bool valid) {
    const long b = row * (long)D_FEAT;
    float e[8];
    #pragma unroll
    for (int j = 0; j < 8; ++j) {
        const int k = c * 8 + j;
        e[j] = valid ? ldm(atoms, b + k, mode) : 0.f;
    }
    #pragma unroll
    for (int w = 0; w < 4; ++w) f2.u[w] = pack2bf(e[2 * w], e[2 * w + 1]);
    #pragma unroll
    for (int j = 0; j < 8; ++j) {
        const int k = 32 + c * 8 + j;
        e[j] = (valid && k < D_FEAT) ? ldm(atoms, b + k, mode) : 0.f;
    }
    #pragma unroll
    for (int w = 0; w < 4; ++w) f3.u[w] = pack2bf(e[2 * w], e[2 * w + 1]);
}

// ---------------------------------------------------------------------------
// K1: MFMA DAG scan. 1 wave/block, 8 DAGs/wave, 2048 blocks.
// A-frag lane map: dag m = lane&15, k = (lane>>4)*8 + j   (per 32-K tile)
// B-frag lane map: outfeat n = lane&15 (+16*nt), k = (lane>>4)*8 + j
// C/D lane map:    outfeat n = lane&15 (+16*nt), dag = (lane>>4)*4 + reg
// outs history [8][48][64] bf16 in LDS (row stride 6160 B); per-node score in scs.
// ---------------------------------------------------------------------------
__global__ __launch_bounds__(64, 1) void k_dag(
    const void* __restrict__ atoms,
    const int*  __restrict__ preds,
    const void* __restrict__ W_single,
    const void* __restrict__ b_single,
    const void* __restrict__ W_merge,
    const void* __restrict__ b_merge,
    const void* __restrict__ att_w,
    const void* __restrict__ dag_w,
    float* __restrict__ last_out,     // [D,62] fp32
    float* __restrict__ score_out)    // [D] fp32
{
    __shared__ char smem[DPB * ROWB + DPB * SCS_STR * 4];   // 50848 B

    const int  lane = threadIdx.x;          // 0..63
    const int  m    = lane & 15;            // A/B/C column id
    const int  quad = lane >> 4;
    const int  mc   = m & 7;                // clamped dag index (8 dags)
    const bool m8   = (m < 8);
    const bool wq   = (quad < 2);           // C rows (dags) 0..7 live in quads 0,1
    const int  d0   = blockIdx.x * DPB;

    // dtype sniff (uniform across grid; bf16 atoms never have |even-half|>=64)
    int mode;
    {
        const unsigned short* a16 = (const unsigned short*)atoms;
        const float v0 = bf2f(a16[2 * lane]);
        const float v1 = bf2f(a16[128 + 2 * lane]);
        const int bad = (!(fabsf(v0) < 64.f)) + (!(fabsf(v1) < 64.f));
        const int cnt = __popcll(__ballot(bad > 0)) + __popcll(__ballot(bad > 1));
        mode = (cnt > 16) ? 1 : 0;
    }

    // B-fragments in registers: W_merge 4nt x 4kt, W_single 4nt x 2kt
    short8 wmF[4][4], wsF[4][2];
    float bm4[4], bs4[4], aw4[4], dw4[4];
    #pragma unroll
    for (int nt = 0; nt < 4; ++nt) {
        const int n = m + 16 * nt;
        #pragma unroll
        for (int kt = 0; kt < 4; ++kt) {
            FragU f;
            #pragma unroll
            for (int w = 0; w < 4; ++w) {
                const int k = kt * 32 + quad * 8 + 2 * w;
                f.u[w] = pack2bf(wm_val(W_merge, n, k, mode), wm_val(W_merge, n, k + 1, mode));
            }
            wmF[nt][kt] = f.v;
        }
        #pragma unroll
        for (int kt = 0; kt < 2; ++kt) {
            FragU f;
            #pragma unroll
            for (int w = 0; w < 4; ++w) {
                const int k = kt * 32 + quad * 8 + 2 * w;
                f.u[w] = pack2bf(ws_val(W_single, n, k, mode), ws_val(W_single, n, k + 1, mode));
            }
            wsF[nt][kt] = f.v;
        }
        bm4[nt] = (n < D_FEAT) ? ldm(b_merge,  n, mode) : 0.f;
        bs4[nt] = (n < D_FEAT) ? ldm(b_single, n, mode) : 0.f;
        aw4[nt] = (n < D_FEAT) ? ldm(att_w,    n, mode) : 0.f;
        dw4[nt] = (n < D_FEAT) ? ldm(dag_w,    n, mode) : 0.f;
    }

    float* scs = (float*)(smem + SCS_OFF);
    const long arow0 = (long)(d0 + mc) * N_NODES;

    // prefetch node 0
    int4 pv = make_int4(-1, -1, -1, -1);
    if (m8) pv = *(const int4*)(preds + (size_t)(d0 + m) * (N_NODES * MAX_PREDS));
    FragU a2, a3;
    load_atom(a2, a3, atoms, arow0, quad, mode, m8);

    #pragma unroll 1
    for (int t = 0; t < N_NODES; ++t) {
        // prefetch node t+1 (independent of the recursion)
        int4 pn = make_int4(-1, -1, -1, -1);
        FragU b2 = a2, b3 = a3;
        if (t < N_NODES - 1) {
            if (m8) pn = *(const int4*)(preds + (size_t)(d0 + m) * (N_NODES * MAX_PREDS)
                                              + (size_t)(t + 1) * 4);
            load_atom(b2, b3, atoms, arow0 + (t + 1), quad, mode, m8);
        }

        const int pm = max(max(pv.x, pv.y), max(pv.z, pv.w));
        const unsigned int mk = (unsigned int)(__ballot(pm >= 0) & 0xFFull);  // bit d = dag d has preds

        f32x4 acc[4] = { {0,0,0,0}, {0,0,0,0}, {0,0,0,0}, {0,0,0,0} };
        f32x4 sac[4] = { {0,0,0,0}, {0,0,0,0}, {0,0,0,0}, {0,0,0,0} };

        if (mk != 0u) {   // merge path (wave-uniform)
            const int p0 = pv.x, p1 = pv.y, p2 = pv.z, p3 = pv.w;
            const int c0 = max(p0, 0), c1 = max(p1, 0), c2 = max(p2, 0), c3 = max(p3, 0);
            const float* srow = scs + mc * SCS_STR;
            float q0 = srow[c0], q1 = srow[c1], q2 = srow[c2], q3 = srow[c3];
            q0 = (p0 >= 0) ? q0 : -1e30f;
            q1 = (p1 >= 0) ? q1 : -1e30f;
            q2 = (p2 >= 0) ? q2 : -1e30f;
            q3 = (p3 >= 0) ? q3 : -1e30f;
            const float mx = fmaxf(fmaxf(q0, q1), fmaxf(q2, q3));
            float e0 = (p0 >= 0) ? __expf(q0 - mx) : 0.f;
            float e1 = (p1 >= 0) ? __expf(q1 - mx) : 0.f;
            float e2 = (p2 >= 0) ? __expf(q2 - mx) : 0.f;
            float e3 = (p3 >= 0) ? __expf(q3 - mx) : 0.f;
            const float inv = 1.f / fmaxf(e0 + e1 + e2 + e3, 1e-30f);
            e0 *= inv; e1 *= inv; e2 *= inv; e3 *= inv;

            // gather predecessor rows + weighted sum -> agg A-frags (kt0, kt1)
            FragU A01[2];
            const char* obase = smem + mc * ROWB;
            #pragma unroll
            for (int cc = 0; cc < 2; ++cc) {
                const int boff = cc * 64 + quad * 16;
                FragU g0, g1, g2, g3;
                g0.v = *(const short8*)(obase + c0 * 128 + boff);
                g1.v = *(const short8*)(obase + c1 * 128 + boff);
                g2.v = *(const short8*)(obase + c2 * 128 + boff);
                g3.v = *(const short8*)(obase + c3 * 128 + boff);
                #pragma unroll
                for (int w = 0; w < 4; ++w) {
                    const float lo = fmaf(e0, pk_lo(g0.u[w]), fmaf(e1, pk_lo(g1.u[w]),
                                     fmaf(e2, pk_lo(g2.u[w]), e3 * pk_lo(g3.u[w]))));
                    const float hi = fmaf(e0, pk_hi(g0.u[w]), fmaf(e1, pk_hi(g1.u[w]),
                                     fmaf(e2, pk_hi(g2.u[w]), e3 * pk_hi(g3.u[w]))));
                    A01[cc].u[w] = pack2bf(lo, hi);
                }
            }
            #pragma unroll
            for (int nt = 0; nt < 4; ++nt) {
                f32x4 c = {0, 0, 0, 0};
                c = __builtin_amdgcn_mfma_f32_16x16x32_bf16(A01[0].v, wmF[nt][0], c, 0, 0, 0);
                c = __builtin_amdgcn_mfma_f32_16x16x32_bf16(A01[1].v, wmF[nt][1], c, 0, 0, 0);
                c = __builtin_amdgcn_mfma_f32_16x16x32_bf16(a2.v,     wmF[nt][2], c, 0, 0, 0);
                c = __builtin_amdgcn_mfma_f32_16x16x32_bf16(a3.v,     wmF[nt][3], c, 0, 0, 0);
                acc[nt] = c;
            }
        }
        if (mk != 0xFFu) {  // single path needed for >=1 dag (always at t=0)
            #pragma unroll
            for (int nt = 0; nt < 4; ++nt) {
                f32x4 c = {0, 0, 0, 0};
                c = __builtin_amdgcn_mfma_f32_16x16x32_bf16(a2.v, wsF[nt][0], c, 0, 0, 0);
                c = __builtin_amdgcn_mfma_f32_16x16x32_bf16(a3.v, wsF[nt][1], c, 0, 0, 0);
                sac[nt] = c;
            }
        }

        // per-element select (hp bit) + bias + relu; unused side is zero-init'd
        float out4[4][4];
        #pragma unroll
        for (int nt = 0; nt < 4; ++nt) {
            #pragma unroll
            for (int r = 0; r < 4; ++r) {
                const int dm = quad * 4 + r;
                const bool hp = (mk >> dm) & 1u;
                const float v = hp ? (acc[nt][r] + bm4[nt]) : (sac[nt][r] + bs4[nt]);
                out4[nt][r] = fmaxf(v, 0.f);
            }
        }

        // write outs history (bf16); cols n>=62 are exact zeros (zeroed B frags)
        #pragma unroll
        for (int nt = 0; nt < 4; ++nt) {
            const int n = m + 16 * nt;
            #pragma unroll
            for (int r = 0; r < 4; ++r) {
                if (wq) {
                    const int dm = quad * 4 + r;
                    *(unsigned short*)(smem + dm * ROWB + t * 128 + n * 2) = f2bf(out4[nt][r]);
                }
            }
        }

        // node score: dot(out, att_w) (dag_w at sink). Reduce over lane&15.
        const bool fin = (t == N_NODES - 1);
        float sr[4] = {0, 0, 0, 0};
        #pragma unroll
        for (int nt = 0; nt < 4; ++nt) {
            const float w = fin ? dw4[nt] : aw4[nt];
            #pragma unroll
            for (int r = 0; r < 4; ++r) sr[r] = fmaf(out4[nt][r], w, sr[r]);
        }
        #pragma unroll
        for (int r = 0; r < 4; ++r) {
            sr[r] += __shfl_xor(sr[r], 1);
            sr[r] += __shfl_xor(sr[r], 2);
            sr[r] += __shfl_xor(sr[r], 4);
            sr[r] += __shfl_xor(sr[r], 8);
        }
        if (m == 0 && wq) {
            #pragma unroll
            for (int r = 0; r < 4; ++r) {
                if (!fin) scs[(quad * 4 + r) * SCS_STR + t] = sr[r];
                else      score_out[d0 + quad * 4 + r] = sr[r];
            }
        }
        if (fin && wq) {
            #pragma unroll
            for (int nt = 0; nt < 4; ++nt) {
                const int n = m + 16 * nt;
                if (n < D_FEAT) {
                    #pragma unroll
                    for (int r = 0; r < 4; ++r)
                        last_out[(size_t)(d0 + quad * 4 + r) * D_FEAT + n] = out4[nt][r];
                }
            }
        }

        pv = pn; a2 = b2; a3 = b3;
    }
}

// ---------------------------------------------------------------------------
// K2: per-chunk online softmax partials. chunk = 64 DAGs per wave, 256 chunks.
// ---------------------------------------------------------------------------
__global__ __launch_bounds__(256) void k_pool(
    const float* __restrict__ last,
    const float* __restrict__ score,
    float* __restrict__ vpart,    // [256,62]
    float* __restrict__ mpart,    // [256]
    float* __restrict__ spart)    // [256]
{
    const int lane = threadIdx.x & 63;
    const int wv   = threadIdx.x >> 6;
    const int c    = blockIdx.x * 4 + wv;
    const int d0   = c * 64;

    const float s = score[d0 + lane];
    float m = s;
    #pragma unroll
    for (int off = 32; off > 0; off >>= 1) m = fmaxf(m, __shfl_xor(m, off));
    const float e = __expf(s - m);
    float den = e;
    #pragma unroll
    for (int off = 32; off > 0; off >>= 1) den += __shfl_xor(den, off);

    float acc = 0.f;
    #pragma unroll 4
    for (int j = 0; j < 64; ++j) {
        const float v = (lane < D_FEAT) ? last[(size_t)(d0 + j) * D_FEAT + lane] : 0.f;
        acc = fmaf(bcast(e, j), v, acc);
    }
    if (lane < D_FEAT) vpart[c * D_FEAT + lane] = acc;
    if (lane == 0) { mpart[c] = m; spart[c] = den; }
}

// ---------------------------------------------------------------------------
// K3: combine 256 chunks (online-softmax merge) + 500-class sigmoid head.
// ---------------------------------------------------------------------------
__global__ __launch_bounds__(256) void k_final(
    const void* __restrict__ atoms,
    const float* __restrict__ vpart,
    const float* __restrict__ mpart,
    const float* __restrict__ spart,
    const void* __restrict__ W_final,
    const void* __restrict__ b_final,
    void* __restrict__ out)
{
    __shared__ float red[256];
    __shared__ float wgt[256];
    __shared__ float pooled[D_FEAT];
    const int tid = threadIdx.x;

    const unsigned short* a16 = (const unsigned short*)atoms;
    const int bad = (!(fabsf(bf2f(a16[2 * (tid & 63)])) < 64.f))
                  + (!(fabsf(bf2f(a16[128 + 2 * (tid & 63)])) < 64.f));
    red[tid] = (float)bad;
    __syncthreads();
    for (int s = 128; s > 0; s >>= 1) {
        if (tid < s) red[tid] += red[tid + s];
        __syncthreads();
    }
    const int mode = (red[0] > 64.f) ? 1 : 0;
    __syncthreads();

    const float m = mpart[tid];
    red[tid] = m;
    __syncthreads();
    for (int s = 128; s > 0; s >>= 1) {
        if (tid < s) red[tid] = fmaxf(red[tid], red[tid + s]);
        __syncthreads();
    }
    const float M = red[0];
    __syncthreads();

    const float w = __expf(m - M);
    wgt[tid] = w;
    red[tid] = w * spart[tid];
    __syncthreads();
    for (int s = 128; s > 0; s >>= 1) {
        if (tid < s) red[tid] += red[tid + s];
        __syncthreads();
    }
    const float denom = red[0];
    __syncthreads();

    if (tid < D_FEAT) {
        float acc = 0.f;
        for (int c = 0; c < 256; ++c) acc = fmaf(wgt[c], vpart[c * D_FEAT + tid], acc);
        pooled[tid] = acc / denom;
    }
    __syncthreads();

    for (int r = tid; r < N_CLASSES; r += 256) {
        float acc = ldm(b_final, r, mode);
        #pragma unroll
        for (int i = 0; i < D_FEAT; ++i)
            acc = fmaf(ldm(W_final, (long)r * D_FEAT + i, mode), pooled[i], acc);
        const float sg = 1.f / (1.f + __expf(-acc));
        if (mode) ((float*)out)[r] = sg;
        else      ((unsigned short*)out)[r] = f2bf(sg);
    }
}

extern "C" void kernel_launch(void* const* d_in, const int* in_sizes, int n_in,
                              void* d_out, int out_size, void* d_ws, size_t ws_size,
                              hipStream_t stream) {
    const void* atoms    = d_in[0];
    const int*  preds    = (const int*)d_in[1];
    const void* W_single = d_in[2];
    const void* b_single = d_in[3];
    const void* W_merge  = d_in[4];
    const void* b_merge  = d_in[5];
    const void* att_w    = d_in[6];
    const void* dag_w    = d_in[7];
    const void* W_final  = d_in[8];
    const void* b_final  = d_in[9];

    float* last  = (float*)d_ws;                     // 16384*62
    float* score = last + (size_t)N_DAGS * D_FEAT;   // 16384
    float* vpart = score + N_DAGS;                   // 256*62
    float* mpart = vpart + 256 * D_FEAT;             // 256
    float* spart = mpart + 256;                      // 256

    k_dag  <<<N_DAGS / DPB, 64, 0, stream>>>(atoms, preds, W_single, b_single, W_merge,
                                             b_merge, att_w, dag_w, last, score);
    k_pool <<<64, 256, 0, stream>>>(last, score, vpart, mpart, spart);
    k_final<<<1, 256, 0, stream>>>(atoms, vpart, mpart, spart, W_final, b_final, d_out);
}

// Round 5
// 649.926 us; speedup vs baseline: 1.7328x; 1.0683x over previous
//
#include <hip/hip_runtime.h>

#define D_FEAT    62
#define N_CLASSES 500
#define N_DAGS    16384
#define N_NODES   48
#define MAX_PREDS 4
#define DPB       8                  // dags per block (one wave of 64)
#define ROWB      6160               // outs row stride bytes: 48*64*2 + 16 pad
#define SCS_OFF   (DPB * ROWB)       // 49280
#define SCS_STR   49                 // scs row stride (floats)

typedef __attribute__((ext_vector_type(8))) short short8;
typedef __attribute__((ext_vector_type(4))) float f32x4;

union FragU { unsigned int u[4]; short8 v; };
struct Raw { unsigned int u[16]; };  // bf16 mode: u[0..7]; fp32 mode: u[0..15]

__device__ __forceinline__ float bf2f(unsigned short u) {
    union { unsigned int i; float f; } v;
    v.i = ((unsigned int)u) << 16;
    return v.f;
}

__device__ __forceinline__ unsigned short f2bf(float f) {
    union { float f; unsigned int i; } v;
    v.f = f;
    unsigned int x = v.i;
    return (unsigned short)((x + 0x7FFFu + ((x >> 16) & 1u)) >> 16);
}

__device__ __forceinline__ unsigned int pack2bf(float a, float b) {
    unsigned int ia = __float_as_uint(a), ib = __float_as_uint(b);
    ia += 0x7FFFu + ((ia >> 16) & 1u);
    ib += 0x7FFFu + ((ib >> 16) & 1u);
    return (ia >> 16) | (ib & 0xFFFF0000u);
}

__device__ __forceinline__ float pk_lo(unsigned int u) { return __uint_as_float(u << 16); }
__device__ __forceinline__ float pk_hi(unsigned int u) { return __uint_as_float(u & 0xFFFF0000u); }

__device__ __forceinline__ float bcast(float x, int k) {
    return __int_as_float(__builtin_amdgcn_readlane(__float_as_int(x), k));
}

__device__ __forceinline__ float ldm(const void* p, long i, int mode) {
    if (mode) return ((const float*)p)[i];
    else      return bf2f(((const unsigned short*)p)[i]);
}

// W_merge value in padded-X coords: X = [agg(62), 0,0, atom(62), 0,0]
__device__ __forceinline__ float wm_val(const void* W, int n, int k, int mode) {
    if (n >= D_FEAT) return 0.f;
    if (k < 62)  return ldm(W, n * 124 + k, mode);
    if (k < 64)  return 0.f;
    if (k < 126) return ldm(W, n * 124 + (k - 2), mode);
    return 0.f;
}

__device__ __forceinline__ float ws_val(const void* W, int n, int k, int mode) {
    if (n >= D_FEAT || k >= D_FEAT) return 0.f;
    return ldm(W, n * 62 + k, mode);
}

// Issue raw atom loads for (row) into r. NO consumption here (true prefetch).
// bf16: row = 124 B; f2 chunk at bytes [quad*16,+16), f3 at [64+quad*16,+16)
// except quad3 clamped to [108,124) (shift applied at pack time). fp32: 248 B
// rows, dwordx2 loads, quad3 f3 clamped to byte 216.
__device__ __forceinline__ void load_raw(Raw& r, const void* atoms, long row,
                                         int quad, int mode) {
    if (mode == 0) {
        const char* base = (const char*)atoms + row * 124;
        const int off3 = (quad < 3) ? (64 + quad * 16) : 108;
        #pragma unroll
        for (int w = 0; w < 4; ++w)
            r.u[w] = *(const unsigned int*)(base + quad * 16 + 4 * w);
        #pragma unroll
        for (int w = 0; w < 4; ++w)
            r.u[4 + w] = *(const unsigned int*)(base + off3 + 4 * w);
    } else {
        const char* base = (const char*)atoms + row * 248;
        const int off3 = (quad < 3) ? (128 + quad * 32) : 216;
        #pragma unroll
        for (int w = 0; w < 4; ++w) {
            uint2 v = *(const uint2*)(base + quad * 32 + 8 * w);
            r.u[2 * w] = v.x; r.u[2 * w + 1] = v.y;
        }
        #pragma unroll
        for (int w = 0; w < 4; ++w) {
            uint2 v = *(const uint2*)(base + off3 + 8 * w);
            r.u[8 + 2 * w] = v.x; r.u[9 + 2 * w] = v.y;
        }
    }
}

// Convert raw regs -> A-fragments (the waitcnt for the prefetch lands here,
// two iterations after issue).
__device__ __forceinline__ void pack_frags(FragU& a2, FragU& a3, const Raw& r,
                                           int quad, int mode) {
    if (mode == 0) {
        #pragma unroll
        for (int w = 0; w < 4; ++w) a2.u[w] = r.u[w];
        if (quad < 3) {
            #pragma unroll
            for (int w = 0; w < 4; ++w) a3.u[w] = r.u[4 + w];
        } else {
            a3.u[0] = r.u[5]; a3.u[1] = r.u[6]; a3.u[2] = r.u[7]; a3.u[3] = 0;
        }
    } else {
        #pragma unroll
        for (int w = 0; w < 4; ++w)
            a2.u[w] = pack2bf(__uint_as_float(r.u[2 * w]), __uint_as_float(r.u[2 * w + 1]));
        if (quad < 3) {
            #pragma unroll
            for (int w = 0; w < 4; ++w)
                a3.u[w] = pack2bf(__uint_as_float(r.u[8 + 2 * w]), __uint_as_float(r.u[9 + 2 * w]));
        } else {
            #pragma unroll
            for (int w = 0; w < 3; ++w)
                a3.u[w] = pack2bf(__uint_as_float(r.u[10 + 2 * w]), __uint_as_float(r.u[11 + 2 * w]));
            a3.u[3] = 0;
        }
    }
}

// ---------------------------------------------------------------------------
// K1: MFMA DAG scan. 1 wave/block, 8 DAGs/wave, 2048 blocks.
// Distance-2 raw prefetch of atoms+preds; pack at use.
// ---------------------------------------------------------------------------
__global__ __launch_bounds__(64, 1) void k_dag(
    const void* __restrict__ atoms,
    const int*  __restrict__ preds,
    const void* __restrict__ W_single,
    const void* __restrict__ b_single,
    const void* __restrict__ W_merge,
    const void* __restrict__ b_merge,
    const void* __restrict__ att_w,
    const void* __restrict__ dag_w,
    float* __restrict__ last_out,     // [D,62] fp32
    float* __restrict__ score_out)    // [D] fp32
{
    __shared__ char smem[DPB * ROWB + DPB * SCS_STR * 4];   // 50848 B

    const int  lane = threadIdx.x;          // 0..63
    const int  m    = lane & 15;
    const int  quad = lane >> 4;
    const int  mc   = m & 7;                // dag index within the group
    const bool wq   = (quad < 2);           // C rows (dags) 0..7 live in quads 0,1
    const int  d0   = blockIdx.x * DPB;

    // dtype sniff (uniform across grid)
    int mode;
    {
        const unsigned short* a16 = (const unsigned short*)atoms;
        const float v0 = bf2f(a16[2 * lane]);
        const float v1 = bf2f(a16[128 + 2 * lane]);
        const int bad = (!(fabsf(v0) < 64.f)) + (!(fabsf(v1) < 64.f));
        const int cnt = __popcll(__ballot(bad > 0)) + __popcll(__ballot(bad > 1));
        mode = (cnt > 16) ? 1 : 0;
    }

    // B-fragments in registers: W_merge 4nt x 4kt, W_single 4nt x 2kt
    short8 wmF[4][4], wsF[4][2];
    float bm4[4], bs4[4], aw4[4], dw4[4];
    #pragma unroll
    for (int nt = 0; nt < 4; ++nt) {
        const int n = m + 16 * nt;
        #pragma unroll
        for (int kt = 0; kt < 4; ++kt) {
            FragU f;
            #pragma unroll
            for (int w = 0; w < 4; ++w) {
                const int k = kt * 32 + quad * 8 + 2 * w;
                f.u[w] = pack2bf(wm_val(W_merge, n, k, mode), wm_val(W_merge, n, k + 1, mode));
            }
            wmF[nt][kt] = f.v;
        }
        #pragma unroll
        for (int kt = 0; kt < 2; ++kt) {
            FragU f;
            #pragma unroll
            for (int w = 0; w < 4; ++w) {
                const int k = kt * 32 + quad * 8 + 2 * w;
                f.u[w] = pack2bf(ws_val(W_single, n, k, mode), ws_val(W_single, n, k + 1, mode));
            }
            wsF[nt][kt] = f.v;
        }
        bm4[nt] = (n < D_FEAT) ? ldm(b_merge,  n, mode) : 0.f;
        bs4[nt] = (n < D_FEAT) ? ldm(b_single, n, mode) : 0.f;
        aw4[nt] = (n < D_FEAT) ? ldm(att_w,    n, mode) : 0.f;
        dw4[nt] = (n < D_FEAT) ? ldm(dag_w,    n, mode) : 0.f;
    }

    float* scs = (float*)(smem + SCS_OFF);
    float* srow = scs + mc * SCS_STR;
    const char* obase = smem + mc * ROWB;
    const long arow0 = (long)(d0 + mc) * N_NODES;
    const int* pbase = preds + (size_t)(d0 + mc) * (N_NODES * MAX_PREDS);

    // one node's full computation (merge/single + MFMA + history/score writes)
    auto node_body = [&](int t, const int4 pv, const FragU a2, const FragU a3) {
        const int pm = max(max(pv.x, pv.y), max(pv.z, pv.w));
        const unsigned int mk = (unsigned int)(__ballot(pm >= 0) & 0xFFull);

        f32x4 acc[4] = { {0,0,0,0}, {0,0,0,0}, {0,0,0,0}, {0,0,0,0} };
        f32x4 sac[4] = { {0,0,0,0}, {0,0,0,0}, {0,0,0,0}, {0,0,0,0} };

        if (mk != 0u) {   // merge path
            const int p0 = pv.x, p1 = pv.y, p2 = pv.z, p3 = pv.w;
            const int c0 = max(p0, 0), c1 = max(p1, 0), c2 = max(p2, 0), c3 = max(p3, 0);
            float q0 = srow[c0], q1 = srow[c1], q2 = srow[c2], q3 = srow[c3];
            q0 = (p0 >= 0) ? q0 : -1e30f;
            q1 = (p1 >= 0) ? q1 : -1e30f;
            q2 = (p2 >= 0) ? q2 : -1e30f;
            q3 = (p3 >= 0) ? q3 : -1e30f;
            const float mx = fmaxf(fmaxf(q0, q1), fmaxf(q2, q3));
            float e0 = (p0 >= 0) ? __expf(q0 - mx) : 0.f;
            float e1 = (p1 >= 0) ? __expf(q1 - mx) : 0.f;
            float e2 = (p2 >= 0) ? __expf(q2 - mx) : 0.f;
            float e3 = (p3 >= 0) ? __expf(q3 - mx) : 0.f;
            const float inv = 1.f / fmaxf(e0 + e1 + e2 + e3, 1e-30f);
            e0 *= inv; e1 *= inv; e2 *= inv; e3 *= inv;

            FragU A01[2];
            #pragma unroll
            for (int cc = 0; cc < 2; ++cc) {
                const int boff = cc * 64 + quad * 16;
                FragU g0, g1, g2, g3;
                g0.v = *(const short8*)(obase + c0 * 128 + boff);
                g1.v = *(const short8*)(obase + c1 * 128 + boff);
                g2.v = *(const short8*)(obase + c2 * 128 + boff);
                g3.v = *(const short8*)(obase + c3 * 128 + boff);
                #pragma unroll
                for (int w = 0; w < 4; ++w) {
                    const float lo = fmaf(e0, pk_lo(g0.u[w]), fmaf(e1, pk_lo(g1.u[w]),
                                     fmaf(e2, pk_lo(g2.u[w]), e3 * pk_lo(g3.u[w]))));
                    const float hi = fmaf(e0, pk_hi(g0.u[w]), fmaf(e1, pk_hi(g1.u[w]),
                                     fmaf(e2, pk_hi(g2.u[w]), e3 * pk_hi(g3.u[w]))));
                    A01[cc].u[w] = pack2bf(lo, hi);
                }
            }
            #pragma unroll
            for (int nt = 0; nt < 4; ++nt) {
                f32x4 c = {0, 0, 0, 0};
                c = __builtin_amdgcn_mfma_f32_16x16x32_bf16(A01[0].v, wmF[nt][0], c, 0, 0, 0);
                c = __builtin_amdgcn_mfma_f32_16x16x32_bf16(A01[1].v, wmF[nt][1], c, 0, 0, 0);
                c = __builtin_amdgcn_mfma_f32_16x16x32_bf16(a2.v,     wmF[nt][2], c, 0, 0, 0);
                c = __builtin_amdgcn_mfma_f32_16x16x32_bf16(a3.v,     wmF[nt][3], c, 0, 0, 0);
                acc[nt] = c;
            }
        }
        if (mk != 0xFFu) {  // single path (always at t=0, ~1% otherwise)
            #pragma unroll
            for (int nt = 0; nt < 4; ++nt) {
                f32x4 c = {0, 0, 0, 0};
                c = __builtin_amdgcn_mfma_f32_16x16x32_bf16(a2.v, wsF[nt][0], c, 0, 0, 0);
                c = __builtin_amdgcn_mfma_f32_16x16x32_bf16(a3.v, wsF[nt][1], c, 0, 0, 0);
                sac[nt] = c;
            }
        }

        float out4[4][4];
        #pragma unroll
        for (int nt = 0; nt < 4; ++nt) {
            #pragma unroll
            for (int r = 0; r < 4; ++r) {
                const int dm = quad * 4 + r;
                const bool hp = (mk >> dm) & 1u;
                const float v = hp ? (acc[nt][r] + bm4[nt]) : (sac[nt][r] + bs4[nt]);
                out4[nt][r] = fmaxf(v, 0.f);
            }
        }

        // history write (bf16)
        #pragma unroll
        for (int nt = 0; nt < 4; ++nt) {
            const int n = m + 16 * nt;
            #pragma unroll
            for (int r = 0; r < 4; ++r) {
                if (wq) {
                    const int dm = quad * 4 + r;
                    *(unsigned short*)(smem + dm * ROWB + t * 128 + n * 2) = f2bf(out4[nt][r]);
                }
            }
        }

        // node score (att_w; dag_w at sink), reduce over n (lane&15 within quad-pair)
        const bool fin = (t == N_NODES - 1);
        float sr[4] = {0, 0, 0, 0};
        #pragma unroll
        for (int nt = 0; nt < 4; ++nt) {
            const float w = fin ? dw4[nt] : aw4[nt];
            #pragma unroll
            for (int r = 0; r < 4; ++r) sr[r] = fmaf(out4[nt][r], w, sr[r]);
        }
        #pragma unroll
        for (int r = 0; r < 4; ++r) {
            sr[r] += __shfl_xor(sr[r], 1);
            sr[r] += __shfl_xor(sr[r], 2);
            sr[r] += __shfl_xor(sr[r], 4);
            sr[r] += __shfl_xor(sr[r], 8);
        }
        if (m == 0 && wq) {
            #pragma unroll
            for (int r = 0; r < 4; ++r) {
                if (!fin) scs[(quad * 4 + r) * SCS_STR + t] = sr[r];
                else      score_out[d0 + quad * 4 + r] = sr[r];
            }
        }
        if (fin && wq) {
            #pragma unroll
            for (int nt = 0; nt < 4; ++nt) {
                const int n = m + 16 * nt;
                if (n < D_FEAT) {
                    #pragma unroll
                    for (int r = 0; r < 4; ++r)
                        last_out[(size_t)(d0 + quad * 4 + r) * D_FEAT + n] = out4[nt][r];
                }
            }
        }
    };

    // prime the distance-2 pipeline
    Raw r0, r1;
    load_raw(r0, atoms, arow0 + 0, quad, mode);
    int4 p0v = *(const int4*)(pbase + 0);
    load_raw(r1, atoms, arow0 + 1, quad, mode);
    int4 p1v = *(const int4*)(pbase + 4);

    #pragma unroll 1
    for (int t = 0; t < N_NODES; t += 2) {
        {   // even node: consume stage 0, refill for t+2
            const int4 p = p0v;
            FragU a2, a3;
            pack_frags(a2, a3, r0, quad, mode);
            if (t + 2 < N_NODES) {
                load_raw(r0, atoms, arow0 + (t + 2), quad, mode);
                p0v = *(const int4*)(pbase + (t + 2) * 4);
            }
            node_body(t, p, a2, a3);
        }
        {   // odd node: consume stage 1, refill for t+3
            const int4 p = p1v;
            FragU a2, a3;
            pack_frags(a2, a3, r1, quad, mode);
            if (t + 3 < N_NODES) {
                load_raw(r1, atoms, arow0 + (t + 3), quad, mode);
                p1v = *(const int4*)(pbase + (t + 3) * 4);
            }
            node_body(t + 1, p, a2, a3);
        }
    }
}

// ---------------------------------------------------------------------------
// K2: per-chunk online softmax partials. chunk = 64 DAGs per wave, 256 chunks.
// ---------------------------------------------------------------------------
__global__ __launch_bounds__(256) void k_pool(
    const float* __restrict__ last,
    const float* __restrict__ score,
    float* __restrict__ vpart,    // [256,62]
    float* __restrict__ mpart,    // [256]
    float* __restrict__ spart)    // [256]
{
    const int lane = threadIdx.x & 63;
    const int wv   = threadIdx.x >> 6;
    const int c    = blockIdx.x * 4 + wv;
    const int d0   = c * 64;

    const float s = score[d0 + lane];
    float m = s;
    #pragma unroll
    for (int off = 32; off > 0; off >>= 1) m = fmaxf(m, __shfl_xor(m, off));
    const float e = __expf(s - m);
    float den = e;
    #pragma unroll
    for (int off = 32; off > 0; off >>= 1) den += __shfl_xor(den, off);

    float acc = 0.f;
    #pragma unroll 4
    for (int j = 0; j < 64; ++j) {
        const float v = (lane < D_FEAT) ? last[(size_t)(d0 + j) * D_FEAT + lane] : 0.f;
        acc = fmaf(bcast(e, j), v, acc);
    }
    if (lane < D_FEAT) vpart[c * D_FEAT + lane] = acc;
    if (lane == 0) { mpart[c] = m; spart[c] = den; }
}

// ---------------------------------------------------------------------------
// K3: combine 256 chunks (online-softmax merge) + 500-class sigmoid head.
// ---------------------------------------------------------------------------
__global__ __launch_bounds__(256) void k_final(
    const void* __restrict__ atoms,
    const float* __restrict__ vpart,
    const float* __restrict__ mpart,
    const float* __restrict__ spart,
    const void* __restrict__ W_final,
    const void* __restrict__ b_final,
    void* __restrict__ out)
{
    __shared__ float red[256];
    __shared__ float wgt[256];
    __shared__ float pooled[D_FEAT];
    const int tid = threadIdx.x;

    const unsigned short* a16 = (const unsigned short*)atoms;
    const int bad = (!(fabsf(bf2f(a16[2 * (tid & 63)])) < 64.f))
                  + (!(fabsf(bf2f(a16[128 + 2 * (tid & 63)])) < 64.f));
    red[tid] = (float)bad;
    __syncthreads();
    for (int s = 128; s > 0; s >>= 1) {
        if (tid < s) red[tid] += red[tid + s];
        __syncthreads();
    }
    const int mode = (red[0] > 64.f) ? 1 : 0;
    __syncthreads();

    const float m = mpart[tid];
    red[tid] = m;
    __syncthreads();
    for (int s = 128; s > 0; s >>= 1) {
        if (tid < s) red[tid] = fmaxf(red[tid], red[tid + s]);
        __syncthreads();
    }
    const float M = red[0];
    __syncthreads();

    const float w = __expf(m - M);
    wgt[tid] = w;
    red[tid] = w * spart[tid];
    __syncthreads();
    for (int s = 128; s > 0; s >>= 1) {
        if (tid < s) red[tid] += red[tid + s];
        __syncthreads();
    }
    const float denom = red[0];
    __syncthreads();

    if (tid < D_FEAT) {
        float acc = 0.f;
        for (int c = 0; c < 256; ++c) acc = fmaf(wgt[c], vpart[c * D_FEAT + tid], acc);
        pooled[tid] = acc / denom;
    }
    __syncthreads();

    for (int r = tid; r < N_CLASSES; r += 256) {
        float acc = ldm(b_final, r, mode);
        #pragma unroll
        for (int i = 0; i < D_FEAT; ++i)
            acc = fmaf(ldm(W_final, (long)r * D_FEAT + i, mode), pooled[i], acc);
        const float sg = 1.f / (1.f + __expf(-acc));
        if (mode) ((float*)out)[r] = sg;
        else      ((unsigned short*)out)[r] = f2bf(sg);
    }
}

extern "C" void kernel_launch(void* const* d_in, const int* in_sizes, int n_in,
                              void* d_out, int out_size, void* d_ws, size_t ws_size,
                              hipStream_t stream) {
    const void* atoms    = d_in[0];
    const int*  preds    = (const int*)d_in[1];
    const void* W_single = d_in[2];
    const void* b_single = d_in[3];
    const void* W_merge  = d_in[4];
    const void* b_merge  = d_in[5];
    const void* att_w    = d_in[6];
    const void* dag_w    = d_in[7];
    const void* W_final  = d_in[8];
    const void* b_final  = d_in[9];

    float* last  = (float*)d_ws;                     // 16384*62
    float* score = last + (size_t)N_DAGS * D_FEAT;   // 16384
    float* vpart = score + N_DAGS;                   // 256*62
    float* mpart = vpart + 256 * D_FEAT;             // 256
    float* spart = mpart + 256;                      // 256

    k_dag  <<<N_DAGS / DPB, 64, 0, stream>>>(atoms, preds, W_single, b_single, W_merge,
                                             b_merge, att_w, dag_w, last, score);
    k_pool <<<64, 256, 0, stream>>>(last, score, vpart, mpart, spart);
    k_final<<<1, 256, 0, stream>>>(atoms, vpart, mpart, spart, W_final, b_final, d_out);
}